// Round 12
// baseline (876.899 us; speedup 1.0000x reference)
//
#include <hip/hip_runtime.h>
#include <hip/hip_bf16.h>
#include <math.h>

// Problem constants (fixed by setup_inputs)
static constexpr int NN   = 30000;   // nodes
static constexpr int EE   = 240000;  // edges (before self loops)
static constexpr int ET   = EE + NN; // edges incl self loops
static constexpr int BB   = 64;      // graphs
static constexpr int HH   = 10;      // heads
static constexpr int CC   = 78;      // per-head dim
static constexpr int CCP  = 80;      // padded per-head dim (16B-aligned slices)
static constexpr int DD   = HH * CC; // 780
static constexpr int DDP  = HH * CCP;// 800 (padded row)
static constexpr int NNP  = 30080;   // nodes padded to x128 (glds GEMM M)
static constexpr int KXP  = 96;      // x K padded to x32
static constexpr int NBP  = 896;     // B^T rows padded to x128
static constexpr int SEQ  = 1000;
static constexpr int EMB  = 128;
static constexpr int LH   = 64;
static constexpr int COMBD = 2 * DD + 128; // 1688
static constexpr int PCHUNK = 64;    // nodes per pool_partial block
static constexpr int USL  = CCP / 2;            // 40 uints per head-row
static constexpr size_t SLICE_U = (size_t)NNP * USL; // uints per head slice

typedef __attribute__((ext_vector_type(8))) short short8;
typedef __attribute__((ext_vector_type(4))) float f32x4;

__device__ __forceinline__ float bflo(unsigned int u) {
    return __uint_as_float(u << 16);
}
__device__ __forceinline__ float bfhi(unsigned int u) {
    return __uint_as_float(u & 0xffff0000u);
}
__device__ __forceinline__ unsigned int pack2bf(float x, float y) {
    __hip_bfloat16 bx = __float2bfloat16(x), by = __float2bfloat16(y);
    unsigned short ux = *reinterpret_cast<unsigned short*>(&bx);
    unsigned short uy = *reinterpret_cast<unsigned short*>(&by);
    return (unsigned int)ux | ((unsigned int)uy << 16);
}
__device__ __forceinline__ float fast_sigmoid(float x) {
    return __builtin_amdgcn_rcpf(1.f + __expf(-x));
}
__device__ __forceinline__ float fast_tanh(float x) {
    float e = __expf(2.f * x);
    return 1.f - 2.f * __builtin_amdgcn_rcpf(e + 1.f);
}
__device__ __forceinline__ void glds16(const unsigned short* g, unsigned short* l) {
    __builtin_amdgcn_global_load_lds(
        (const __attribute__((address_space(1))) unsigned int*)g,
        (__attribute__((address_space(3))) unsigned int*)l, 16, 0, 0);
}

// ======== glds MFMA GEMM, SLICED epilogue: C[col/78][row][col%78] bf16 ========
// A [Mp,Kp] row-major bf16 (pads allocated, K-pads zero), Bt [Np,Kp].
// Kp%32==0, grid covers Mp/128 x Np/128. Output written only row<M, col<N.
__global__ __launch_bounds__(256) void gemm_glds_sl(const __hip_bfloat16* __restrict__ A,
                                                    const __hip_bfloat16* __restrict__ Bt,
                                                    __hip_bfloat16* __restrict__ C,
                                                    int M, int N, int Kp) {
    __shared__ unsigned short As[128 * 32];
    __shared__ unsigned short Bs[128 * 32];
    const int tid  = threadIdx.x;
    const int lane = tid & 63, wid = tid >> 6;
    const int wr = wid >> 1, wc = wid & 1;
    const int l15 = lane & 15, l4 = lane >> 4;
    int l = blockIdx.y * gridDim.x + blockIdx.x;
    {   // bijective XCD swizzle (m204)
        int nwg = gridDim.x * gridDim.y;
        int q = nwg >> 3, r = nwg & 7;
        int xcd = l & 7, idx = l >> 3;
        l = (xcd < r) ? (xcd * (q + 1) + idx) : (r * (q + 1) + (xcd - r) * q + idx);
    }
    const int bm = (l / gridDim.x) * 128;
    const int bn = (l % gridDim.x) * 128;
    const unsigned short* Au = (const unsigned short*)A;
    const unsigned short* Bu = (const unsigned short*)Bt;
    const int lrow = lane >> 2, lseg = (lane & 3) * 8;

    f32x4 acc[4][4];
#pragma unroll
    for (int m = 0; m < 4; ++m)
#pragma unroll
        for (int n = 0; n < 4; ++n) acc[m][n] = (f32x4){0.f, 0.f, 0.f, 0.f};

    for (int k0 = 0; k0 < Kp; k0 += 32) {
#pragma unroll
        for (int c = 0; c < 2; ++c) {
            int rbase = wid * 32 + c * 16;
            glds16(Au + (size_t)(bm + rbase + lrow) * Kp + k0 + lseg, &As[rbase * 32]);
            glds16(Bu + (size_t)(bn + rbase + lrow) * Kp + k0 + lseg, &Bs[rbase * 32]);
        }
        __syncthreads();
        short8 a[4], b[4];
#pragma unroll
        for (int m = 0; m < 4; ++m)
            a[m] = *reinterpret_cast<const short8*>(&As[(wr * 64 + m * 16 + l15) * 32 + l4 * 8]);
#pragma unroll
        for (int n = 0; n < 4; ++n)
            b[n] = *reinterpret_cast<const short8*>(&Bs[(wc * 64 + n * 16 + l15) * 32 + l4 * 8]);
#pragma unroll
        for (int m = 0; m < 4; ++m)
#pragma unroll
            for (int n = 0; n < 4; ++n)
                acc[m][n] = __builtin_amdgcn_mfma_f32_16x16x32_bf16(a[m], b[n], acc[m][n], 0, 0, 0);
        __syncthreads();
    }
#pragma unroll
    for (int m = 0; m < 4; ++m)
#pragma unroll
        for (int n = 0; n < 4; ++n)
#pragma unroll
            for (int r = 0; r < 4; ++r) {
                int row = bm + wr * 64 + m * 16 + l4 * 4 + r;
                int col = bn + wc * 64 + n * 16 + l15;
                if (row < M && col < N) {
                    int sl = col / CC, c = col % CC;
                    C[(size_t)sl * NNP * CCP + (size_t)row * CCP + c] =
                        __float2bfloat16(acc[m][n][r]);
                }
            }
}

// ======== legacy VGPR-staging MFMA GEMM (conv GEMM: K=1000 not %32) ========
__global__ __launch_bounds__(256) void gemm_bf16_mfma(const __hip_bfloat16* __restrict__ A,
                                                      const __hip_bfloat16* __restrict__ Bt,
                                                      float* __restrict__ C,
                                                      int M, int N, int K, int ldc) {
    constexpr int LDS_S = 40;
    __shared__ unsigned short As[128 * LDS_S];
    __shared__ unsigned short Bs[128 * LDS_S];
    const int tid  = threadIdx.x;
    const int lane = tid & 63, wid = tid >> 6;
    const int wr = wid >> 1, wc = wid & 1;
    const int l15 = lane & 15, l4 = lane >> 4;
    int l = blockIdx.y * gridDim.x + blockIdx.x;
    {
        int nwg = gridDim.x * gridDim.y;
        int q = nwg >> 3, r = nwg & 7;
        int xcd = l & 7, idx = l >> 3;
        l = (xcd < r) ? (xcd * (q + 1) + idx) : (r * (q + 1) + (xcd - r) * q + idx);
    }
    const int bm = (l / gridDim.x) * 128;
    const int bn = (l % gridDim.x) * 128;
    const int tr = tid >> 2, tc = (tid & 3) * 8;

    const unsigned short* Au = (const unsigned short*)A;
    const unsigned short* Bu = (const unsigned short*)Bt;

    f32x4 acc[4][4];
#pragma unroll
    for (int m = 0; m < 4; ++m)
#pragma unroll
        for (int n = 0; n < 4; ++n) acc[m][n] = (f32x4){0.f, 0.f, 0.f, 0.f};

    for (int k0 = 0; k0 < K; k0 += 32) {
#pragma unroll
        for (int half = 0; half < 2; ++half) {
            int row = tr + half * 64;
            { // A tile
                int grow = bm + row;
                short8 sv;
                if (grow < M && k0 + tc + 8 <= K) {
                    const unsigned int* p = (const unsigned int*)(Au + (size_t)grow * K + k0 + tc);
#pragma unroll
                    for (int j = 0; j < 4; ++j) {
                        unsigned int u = p[j];
                        sv[2 * j]     = (short)(u & 0xffffu);
                        sv[2 * j + 1] = (short)(u >> 16);
                    }
                } else {
#pragma unroll
                    for (int j = 0; j < 8; ++j) {
                        int gk = k0 + tc + j;
                        sv[j] = (grow < M && gk < K) ? (short)Au[(size_t)grow * K + gk] : (short)0;
                    }
                }
                *reinterpret_cast<short8*>(&As[row * LDS_S + tc]) = sv;
            }
            { // B^T tile
                int grow = bn + row;
                short8 sv;
                if (grow < N && k0 + tc + 8 <= K) {
                    const unsigned int* p = (const unsigned int*)(Bu + (size_t)grow * K + k0 + tc);
#pragma unroll
                    for (int j = 0; j < 4; ++j) {
                        unsigned int u = p[j];
                        sv[2 * j]     = (short)(u & 0xffffu);
                        sv[2 * j + 1] = (short)(u >> 16);
                    }
                } else {
#pragma unroll
                    for (int j = 0; j < 8; ++j) {
                        int gk = k0 + tc + j;
                        sv[j] = (grow < N && gk < K) ? (short)Bu[(size_t)grow * K + gk] : (short)0;
                    }
                }
                *reinterpret_cast<short8*>(&Bs[row * LDS_S + tc]) = sv;
            }
        }
        __syncthreads();
        short8 a[4], b[4];
#pragma unroll
        for (int m = 0; m < 4; ++m)
            a[m] = *reinterpret_cast<const short8*>(&As[(wr * 64 + m * 16 + l15) * LDS_S + l4 * 8]);
#pragma unroll
        for (int n = 0; n < 4; ++n)
            b[n] = *reinterpret_cast<const short8*>(&Bs[(wc * 64 + n * 16 + l15) * LDS_S + l4 * 8]);
#pragma unroll
        for (int m = 0; m < 4; ++m)
#pragma unroll
            for (int n = 0; n < 4; ++n)
                acc[m][n] = __builtin_amdgcn_mfma_f32_16x16x32_bf16(a[m], b[n], acc[m][n], 0, 0, 0);
        __syncthreads();
    }
#pragma unroll
    for (int m = 0; m < 4; ++m)
#pragma unroll
        for (int n = 0; n < 4; ++n)
#pragma unroll
            for (int r = 0; r < 4; ++r) {
                int row = bm + wr * 64 + m * 16 + l4 * 4 + r;
                int col = bn + wc * 64 + n * 16 + l15;
                if (row < M && col < N)
                    C[(size_t)row * ldc + col] = acc[m][n][r];
            }
}

// ---------------- conversions / padding ----------------
__global__ void pad_x(const float* __restrict__ x, __hip_bfloat16* __restrict__ xp) {
    int idx = blockIdx.x * blockDim.x + threadIdx.x;
    if (idx >= NNP * KXP) return;
    int r = idx / KXP, c = idx % KXP;
    float v = (r < NN && c < CC) ? x[(size_t)r * CC + c] : 0.f;
    xp[idx] = __float2bfloat16(v);
}

__global__ void pad_wT(const float* __restrict__ w, __hip_bfloat16* __restrict__ wt) {
    int idx = blockIdx.x * blockDim.x + threadIdx.x;
    if (idx >= NBP * KXP) return;
    int n = idx / KXP, k = idx % KXP;
    float v = (n < DD && k < CC) ? w[(size_t)k * DD + n] : 0.f;
    wt[idx] = __float2bfloat16(v);
}

// gcn_w [DD][DD] -> wt [NBP][DDP] with head-padded K map (matches dense h rows)
__global__ void pad_gcwT(const float* __restrict__ w, __hip_bfloat16* __restrict__ wt) {
    int idx = blockIdx.x * blockDim.x + threadIdx.x;
    if (idx >= NBP * DDP) return;
    int n = idx / DDP, kp = idx % DDP;
    int kc = kp % CCP;
    int k = (kp / CCP) * CC + kc;
    float v = (n < DD && kc < CC) ? w[(size_t)k * DD + n] : 0.f;
    wt[idx] = __float2bfloat16(v);
}

__global__ void transpose_f32(const float* __restrict__ in, float* __restrict__ out,
                              int Kdim, int Ndim) {
    int idx = blockIdx.x * blockDim.x + threadIdx.x;
    if (idx >= Kdim * Ndim) return;
    int n = idx / Kdim, k = idx % Kdim;
    out[idx] = in[(size_t)k * Ndim + n];
}

__global__ void pad_att(const float* __restrict__ att, float* __restrict__ att_p) {
    int idx = blockIdx.x * blockDim.x + threadIdx.x;
    if (idx >= HH * CCP) return;
    int h = idx / CCP, c = idx % CCP;
    att_p[idx] = (c < CC) ? att[h * CC + c] : 0.f;
}

// zero pad lanes (c=78,79) of each head slice, rows < NN, both matrices
__global__ void zero_pads(unsigned int* __restrict__ a, unsigned int* __restrict__ b) {
    int idx = blockIdx.x * blockDim.x + threadIdx.x;
    if (idx >= NN * HH) return;
    int n = idx / HH, h = idx % HH;
    size_t p = (size_t)h * SLICE_U + (size_t)n * USL + (USL - 1);
    a[p] = 0u;
    b[p] = 0u;
}

// ------------- skinny GEMM: wave-per-output split-K. Bt is [N][K]. -------------
template <int ACT>
__global__ __launch_bounds__(256) void gemm_skinny(const float* __restrict__ A,
                                                   const float* __restrict__ Bt,
                                                   const float* __restrict__ bias,
                                                   float* __restrict__ C,
                                                   int M, int N, int K, int ldc) {
    int oidx = blockIdx.x * 4 + (threadIdx.x >> 6);
    int lane = threadIdx.x & 63;
    if (oidx >= M * N) return;
    int row = oidx / N, col = oidx % N;
    const float4* a = (const float4*)(A + (size_t)row * K);
    const float4* b = (const float4*)(Bt + (size_t)col * K);
    int K4 = K >> 2;
    float s = 0.f;
    for (int i = lane; i < K4; i += 64) {
        float4 x = a[i], y = b[i];
        s += x.x * y.x + x.y * y.y + x.z * y.z + x.w * y.w;
    }
#pragma unroll
    for (int off = 32; off; off >>= 1) s += __shfl_xor(s, off);
    if (lane == 0) {
        s += bias[col];
        if (ACT == 1) s = fmaxf(s, 0.f);
        C[(size_t)row * ldc + col] = s;
    }
}

// ---------------- CSR construction ----------------
__global__ void deg_count(const int* __restrict__ ei, int* __restrict__ deg) {
    int e = blockIdx.x * blockDim.x + threadIdx.x;
    if (e >= ET) return;
    int d = (e < EE) ? ei[EE + e] : (e - EE);
    atomicAdd(&deg[d], 1);
}

__global__ __launch_bounds__(1024) void scan_kernel(const int* __restrict__ deg,
                                                    int* __restrict__ offs) {
    __shared__ int lds[1024];
    int tid = threadIdx.x;
    const int chunk = (NN + 1023) / 1024;
    int base = tid * chunk;
    int s = 0;
    for (int i = 0; i < chunk; ++i) {
        int idx = base + i;
        if (idx < NN) s += deg[idx];
    }
    lds[tid] = s;
    __syncthreads();
    for (int d = 1; d < 1024; d <<= 1) {
        int v = (tid >= d) ? lds[tid - d] : 0;
        __syncthreads();
        lds[tid] += v;
        __syncthreads();
    }
    int run = (tid == 0) ? 0 : lds[tid - 1];
    for (int i = 0; i < chunk; ++i) {
        int idx = base + i;
        if (idx < NN) { offs[idx] = run; run += deg[idx]; }
    }
    if (tid == 1023) offs[NN] = lds[1023];
}

__global__ void csr_fill(const int* __restrict__ ei, const int* __restrict__ offs,
                         int* __restrict__ cursor, int* __restrict__ csr_src,
                         int* __restrict__ csr_dst) {
    int e = blockIdx.x * blockDim.x + threadIdx.x;
    if (e >= ET) return;
    int s = (e < EE) ? ei[e] : (e - EE);
    int d = (e < EE) ? ei[EE + e] : (e - EE);
    int pos = atomicAdd(&cursor[d], 1);
    int slot = offs[d] + pos;
    csr_src[slot] = s;
    csr_dst[slot] = d;
}

__global__ void dinv_kernel(const int* __restrict__ deg, float* __restrict__ dinv) {
    int n = blockIdx.x * blockDim.x + threadIdx.x;
    if (n >= NN) return;
    float dg = (float)deg[n];
    dinv[n] = (dg > 0.f) ? 1.f / sqrtf(dg) : 0.f;
}

// ---------------- GATv2 (head-sliced bf16 gathers) ----------------
__device__ __forceinline__ float dot2lr(unsigned int a, unsigned int b, float w0, float w1) {
    float v0 = bflo(a) + bflo(b);
    float v1 = bfhi(a) + bfhi(b);
    v0 = (v0 > 0.f) ? v0 : 0.2f * v0;
    v1 = (v1 > 0.f) ? v1 : 0.2f * v1;
    return w0 * v0 + w1 * v1;
}

// grid: (ceil(ET/256), HH) -> head-pure blocks, per-XCD working set ~ one slice
__global__ void gat_logits(const unsigned short* __restrict__ xl_sl,
                           const unsigned short* __restrict__ xr_sl,
                           const float* __restrict__ att_p, const int* __restrict__ csr_src,
                           const int* __restrict__ csr_dst, float* __restrict__ logit_hm) {
    int i = blockIdx.x * blockDim.x + threadIdx.x;
    int h = blockIdx.y;
    if (i >= ET) return;
    int s = csr_src[i], d = csr_dst[i];
    const uint4* pl = (const uint4*)(xl_sl + (size_t)h * NNP * CCP + (size_t)s * CCP);
    const uint4* pr = (const uint4*)(xr_sl + (size_t)h * NNP * CCP + (size_t)d * CCP);
    const float* pa = att_p + h * CCP;
    float acc = 0.f;
#pragma unroll
    for (int q = 0; q < CCP / 8; ++q) {
        uint4 a = pl[q], b = pr[q];
        const float* p8 = pa + q * 8;
        acc += dot2lr(a.x, b.x, p8[0], p8[1]);
        acc += dot2lr(a.y, b.y, p8[2], p8[3]);
        acc += dot2lr(a.z, b.z, p8[4], p8[5]);
        acc += dot2lr(a.w, b.w, p8[6], p8[7]);
    }
    logit_hm[(size_t)h * ET + i] = acc;
}

__global__ void gat_softmax(const int* __restrict__ offs, float* __restrict__ logit_hm) {
    int idx = blockIdx.x * blockDim.x + threadIdx.x;
    if (idx >= NN * HH) return;
    int n = idx / HH, h = idx % HH;
    int i0 = offs[n], i1 = offs[n + 1];
    float* lg = logit_hm + (size_t)h * ET;
    float m = -1e30f;
    for (int i = i0; i < i1; ++i) m = fmaxf(m, lg[i]);
    float den = 0.f;
    for (int i = i0; i < i1; ++i) {
        float e = __expf(lg[i] - m);
        lg[i] = e;
        den += e;
    }
    float inv = __builtin_amdgcn_rcpf(den);
    for (int i = i0; i < i1; ++i) lg[i] *= inv;
}

// reads head-sliced xl (uint lanes), writes DENSE-padded h rows (pads zero)
__global__ __launch_bounds__(256) void gat_aggregate(const int* __restrict__ offs,
                                                     const int* __restrict__ csr_src,
                                                     const float* __restrict__ alpha_hm,
                                                     const unsigned int* __restrict__ xl_sl,
                                                     const float* __restrict__ gat_b,
                                                     unsigned int* __restrict__ hout) {
    int n = blockIdx.x;
    int tid = threadIdx.x;
    int i0 = offs[n], i1 = offs[n + 1];
    const int U = DDP / 2;  // 400
    int u0 = tid, u1 = tid + 256;
    bool v1 = (u1 < U);
    int h0 = u0 / USL, c0 = u0 % USL;
    int h1 = v1 ? u1 / USL : 0, c1 = v1 ? u1 % USL : 0;
    const unsigned int* s0 = xl_sl + (size_t)h0 * SLICE_U + c0;
    const unsigned int* s1 = xl_sl + (size_t)h1 * SLICE_U + c1;
    const float* a0p = alpha_hm + (size_t)h0 * ET;
    const float* a1p = alpha_hm + (size_t)h1 * ET;
    float lo0 = 0.f, hi0 = 0.f, lo1 = 0.f, hi1 = 0.f;
    for (int i = i0; i < i1; ++i) {
        int src = csr_src[i];
        unsigned int w0 = s0[(size_t)src * USL];
        float p0 = a0p[i];
        lo0 += p0 * bflo(w0);
        hi0 += p0 * bfhi(w0);
        if (v1) {
            unsigned int w1 = s1[(size_t)src * USL];
            float p1 = a1p[i];
            lo1 += p1 * bflo(w1);
            hi1 += p1 * bfhi(w1);
        }
    }
    unsigned int ov0 = 0u, ov1 = 0u;
    if (c0 != USL - 1) {
        int d = h0 * CC + 2 * c0;
        float x = lo0 + gat_b[d];     x = (x > 0.f) ? x : __expf(x) - 1.f;
        float y = hi0 + gat_b[d + 1]; y = (y > 0.f) ? y : __expf(y) - 1.f;
        ov0 = pack2bf(x, y);
    }
    hout[(size_t)n * U + u0] = ov0;
    if (v1) {
        if (c1 != USL - 1) {
            int d = h1 * CC + 2 * c1;
            float x = lo1 + gat_b[d];     x = (x > 0.f) ? x : __expf(x) - 1.f;
            float y = hi1 + gat_b[d + 1]; y = (y > 0.f) ? y : __expf(y) - 1.f;
            ov1 = pack2bf(x, y);
        }
        hout[(size_t)n * U + u1] = ov1;
    }
}

// ------------- GCN aggregation (head-sliced in/out, uint lanes) -------------
__global__ __launch_bounds__(256) void gcn_aggregate(const int* __restrict__ offs,
                                                     const int* __restrict__ csr_src,
                                                     const float* __restrict__ dinv,
                                                     const unsigned int* __restrict__ hw_sl,
                                                     const float* __restrict__ gcn_b,
                                                     unsigned int* __restrict__ g_sl) {
    int n = blockIdx.x;
    int tid = threadIdx.x;
    float din = dinv[n];
    int i0 = offs[n], i1 = offs[n + 1];
    const int U = DDP / 2;
    int u0 = tid, u1 = tid + 256;
    bool v1 = (u1 < U);
    int h0 = u0 / USL, c0 = u0 % USL;
    int h1 = v1 ? u1 / USL : 0, c1 = v1 ? u1 % USL : 0;
    const unsigned int* s0 = hw_sl + (size_t)h0 * SLICE_U + c0;
    const unsigned int* s1 = hw_sl + (size_t)h1 * SLICE_U + c1;
    float lo0 = 0.f, hi0 = 0.f, lo1 = 0.f, hi1 = 0.f;
    for (int i = i0; i < i1; ++i) {
        int src = csr_src[i];
        float w = dinv[src] * din;
        unsigned int w0 = s0[(size_t)src * USL];
        lo0 += w * bflo(w0);
        hi0 += w * bfhi(w0);
        if (v1) {
            unsigned int w1 = s1[(size_t)src * USL];
            lo1 += w * bflo(w1);
            hi1 += w * bfhi(w1);
        }
    }
    if (c0 != USL - 1) {
        int d = h0 * CC + 2 * c0;
        float x = fmaxf(lo0 + gcn_b[d], 0.f);
        float y = fmaxf(hi0 + gcn_b[d + 1], 0.f);
        g_sl[(size_t)h0 * SLICE_U + (size_t)n * USL + c0] = pack2bf(x, y);
    }
    if (v1 && c1 != USL - 1) {
        int d = h1 * CC + 2 * c1;
        float x = fmaxf(lo1 + gcn_b[d], 0.f);
        float y = fmaxf(hi1 + gcn_b[d + 1], 0.f);
        g_sl[(size_t)h1 * SLICE_U + (size_t)n * USL + c1] = pack2bf(x, y);
    }
}

// ---------------- pooling ----------------
__global__ void graph_ranges(const int* __restrict__ batch, int* __restrict__ gstart,
                             int* __restrict__ gend) {
    int n = blockIdx.x * blockDim.x + threadIdx.x;
    if (n >= NN) return;
    int b = batch[n];
    if (n == 0 || batch[n - 1] != b) gstart[b] = n;
    if (n == NN - 1 || batch[n + 1] != b) gend[b] = n + 1;
}

// g head-sliced (uint lanes). g >= 0 (ReLU): atomicMax on uint bits exact.
__global__ __launch_bounds__(256) void pool_partial(const unsigned int* __restrict__ g_sl,
                                                    const int* __restrict__ batch,
                                                    float* __restrict__ pmax,
                                                    float* __restrict__ psum) {
    int chunk0 = blockIdx.x * PCHUNK;
    int tid = threadIdx.x;
    __shared__ int bsh[PCHUNK];
    for (int i = tid; i < PCHUNK; i += 256) {
        int n = chunk0 + i;
        bsh[i] = (n < NN) ? batch[n] : -1;
    }
    __syncthreads();
    const int U = DDP / 2;
    int u0 = tid, u1 = tid + 256;
    bool v1 = (u1 < U);
    int h0 = u0 / USL, c0 = u0 % USL;
    int h1 = v1 ? u1 / USL : 0, c1 = v1 ? u1 % USL : 0;
    const unsigned int* s0 = g_sl + (size_t)h0 * SLICE_U + c0;
    const unsigned int* s1 = g_sl + (size_t)h1 * SLICE_U + c1;
    float mA = 0.f, mB = 0.f, mC = 0.f, mD = 0.f;
    float sA = 0.f, sB = 0.f, sC = 0.f, sD = 0.f;
    int curb = bsh[0];
    auto flush = [&](int b) {
        if (b >= 0) {
            if (c0 != USL - 1) {
                int d = h0 * CC + 2 * c0;
                atomicMax((unsigned int*)&pmax[(size_t)b * DD + d], __float_as_uint(mA));
                atomicAdd(&psum[(size_t)b * DD + d], sA);
                atomicMax((unsigned int*)&pmax[(size_t)b * DD + d + 1], __float_as_uint(mB));
                atomicAdd(&psum[(size_t)b * DD + d + 1], sB);
            }
            if (v1 && c1 != USL - 1) {
                int d = h1 * CC + 2 * c1;
                atomicMax((unsigned int*)&pmax[(size_t)b * DD + d], __float_as_uint(mC));
                atomicAdd(&psum[(size_t)b * DD + d], sC);
                atomicMax((unsigned int*)&pmax[(size_t)b * DD + d + 1], __float_as_uint(mD));
                atomicAdd(&psum[(size_t)b * DD + d + 1], sD);
            }
        }
        mA = mB = mC = mD = 0.f;
        sA = sB = sC = sD = 0.f;
    };
    for (int i = 0; i < PCHUNK; ++i) {
        int n = chunk0 + i;
        if (n >= NN) break;
        int b = bsh[i];
        if (b != curb) { flush(curb); curb = b; }
        unsigned int w0 = s0[(size_t)n * USL];
        float x = bflo(w0), y = bfhi(w0);
        mA = fmaxf(mA, x); sA += x;
        mB = fmaxf(mB, y); sB += y;
        if (v1) {
            unsigned int w1 = s1[(size_t)n * USL];
            float z = bflo(w1), t = bfhi(w1);
            mC = fmaxf(mC, z); sC += z;
            mD = fmaxf(mD, t); sD += t;
        }
    }
    flush(curb);
}

__global__ void pool_finalize(const float* __restrict__ pmax, const float* __restrict__ psum,
                              const int* __restrict__ gstart, const int* __restrict__ gend,
                              float* __restrict__ comb) {
    int idx = blockIdx.x * blockDim.x + threadIdx.x;
    if (idx >= BB * DD) return;
    int b = idx / DD, d = idx % DD;
    float cnt = fmaxf((float)(gend[b] - gstart[b]), 1.f);
    comb[(size_t)b * COMBD + d] = pmax[idx];
    comb[(size_t)b * COMBD + DD + d] = psum[idx] / cnt;
}

// ---------------- protein branch ----------------
__global__ void proj26_kernel(const float* __restrict__ emb,
                              const float* __restrict__ Wih_f, const float* __restrict__ bih_f,
                              const float* __restrict__ bhh_f,
                              const float* __restrict__ Wih_b, const float* __restrict__ bih_b,
                              const float* __restrict__ bhh_b, float* __restrict__ proj) {
    int dir = blockIdx.x, row = blockIdx.y, j = threadIdx.x;
    const float* W = dir ? Wih_b : Wih_f;
    const float* b1 = dir ? bih_b : bih_f;
    const float* b2 = dir ? bhh_b : bhh_f;
    float acc = b1[j] + b2[j];
    const float* e = emb + row * EMB;
    const float* w = W + j * EMB;
    for (int k = 0; k < EMB; ++k) acc += e[k] * w[k];
    proj[(dir * 26 + row) * 256 + j] = acc;
}

__global__ __launch_bounds__(256) void lstm_kernel(const int* __restrict__ target,
                                                   const float* __restrict__ proj26,
                                                   const float* __restrict__ Whh_f,
                                                   const float* __restrict__ Whh_b,
                                                   float* __restrict__ hcat) {
    int n = blockIdx.x;
    int dir = blockIdx.y;
    int tid = threadIdx.x;
    const float* Whh = dir ? Whh_b : Whh_f;
    const float* proj = proj26 + dir * 26 * 256;
    const int gate = tid >> 6;  // 0=i 1=f 2=g 3=o
    float w[LH];
#pragma unroll
    for (int u4 = 0; u4 < LH / 4; ++u4) {
        float4 v = *reinterpret_cast<const float4*>(Whh + tid * LH + u4 * 4);
        w[u4 * 4 + 0] = v.x; w[u4 * 4 + 1] = v.y;
        w[u4 * 4 + 2] = v.z; w[u4 * 4 + 3] = v.w;
    }
    __shared__ float h_lds[LH];
    __shared__ float z_lds[256];
    float c_reg = 0.f;
    if (tid < LH) h_lds[tid] = 0.f;
    __syncthreads();
    for (int s = 0; s < BB; ++s) {
        int t = dir ? (BB - 1 - s) : s;
        int tgt = target[t * SEQ + n];
        float a0 = 0.f, a1 = 0.f, a2 = 0.f, a3 = 0.f;
#pragma unroll
        for (int u = 0; u < LH; u += 4) {
            a0 += w[u] * h_lds[u];
            a1 += w[u + 1] * h_lds[u + 1];
            a2 += w[u + 2] * h_lds[u + 2];
            a3 += w[u + 3] * h_lds[u + 3];
        }
        float z = proj[tgt * 256 + tid] + a0 + a1 + a2 + a3;
        z_lds[tid] = (gate == 2) ? fast_tanh(z) : fast_sigmoid(z);
        __syncthreads();
        if (tid < LH) {
            float ig = z_lds[tid];
            float fg = z_lds[LH + tid];
            float gg = z_lds[2 * LH + tid];
            float og = z_lds[3 * LH + tid];
            float c = fg * c_reg + ig * gg;
            float h = og * fast_tanh(c);
            c_reg = c;
            h_lds[tid] = h;
            hcat[((size_t)t * SEQ + n) * 128 + dir * LH + tid] = h;
        }
        __syncthreads();
    }
}

// hcat[b][i][h] f32 -> hcatT[b][h][i] bf16 (LDS tiled transpose)
__global__ __launch_bounds__(256) void transpose_hcat(const float* __restrict__ hcat,
                                                      unsigned short* __restrict__ hcatT) {
    int b = blockIdx.z;
    int i0 = blockIdx.y * 32;
    int h0 = blockIdx.x * 32;
    int th = threadIdx.x & 31;
    int ti = threadIdx.x >> 5;
    __shared__ float t[32][33];
#pragma unroll
    for (int r = 0; r < 4; ++r) {
        int i = i0 + ti + r * 8;
        if (i < SEQ) t[ti + r * 8][th] = hcat[((size_t)b * SEQ + i) * 128 + h0 + th];
    }
    __syncthreads();
#pragma unroll
    for (int r = 0; r < 4; ++r) {
        int h = h0 + ti + r * 8;
        int i = i0 + th;
        if (i < SEQ) {
            unsigned int u = __float_as_uint(t[th][ti + r * 8]);
            unsigned int lsb = (u >> 16) & 1u;
            u += 0x7fffu + lsb;
            hcatT[((size_t)b * 128 + h) * SEQ + i] = (unsigned short)(u >> 16);
        }
    }
}

// conv_w[o][i][k] f32 -> wT[o*8+k][i] bf16
__global__ void reshape_convw(const float* __restrict__ conv_w, __hip_bfloat16* __restrict__ wT) {
    int idx = blockIdx.x * blockDim.x + threadIdx.x;
    if (idx >= 256 * SEQ) return;
    int np = idx / SEQ, i = idx % SEQ;
    int o = np >> 3, k = np & 7;
    wT[idx] = __float2bfloat16(conv_w[((size_t)o * SEQ + i) * 8 + k]);
}

// out[b][o][p] = sum_k T[(b*128+p+k)][o*8+k] + conv_b[o]
__global__ void conv_finalize(const float* __restrict__ T, const float* __restrict__ conv_b,
                              float* __restrict__ convout) {
    int idx = blockIdx.x * blockDim.x + threadIdx.x;
    if (idx >= BB * 32 * 121) return;
    int p = idx % 121;
    int o = (idx / 121) % 32;
    int b = idx / (121 * 32);
    float acc = conv_b[o];
#pragma unroll
    for (int k = 0; k < 8; ++k)
        acc += T[(size_t)(b * 128 + p + k) * 256 + o * 8 + k];
    convout[(size_t)b * 3872 + o * 121 + p] = acc;
}

// ---------------- launcher ----------------
extern "C" void kernel_launch(void* const* d_in, const int* in_sizes, int n_in,
                              void* d_out, int out_size, void* d_ws, size_t ws_size,
                              hipStream_t stream) {
    const float* x      = (const float*)d_in[0];
    const int*   ei     = (const int*)d_in[1];
    const int*   batch  = (const int*)d_in[2];
    const int*   target = (const int*)d_in[3];
    const float* Wl     = (const float*)d_in[4];
    const float* Wr     = (const float*)d_in[5];
    const float* att    = (const float*)d_in[6];
    const float* gat_b  = (const float*)d_in[7];
    const float* gcn_w  = (const float*)d_in[8];
    const float* gcn_b  = (const float*)d_in[9];
    const float* emb    = (const float*)d_in[10];
    const float* Wih_f  = (const float*)d_in[11];
    const float* Whh_f  = (const float*)d_in[12];
    const float* bih_f  = (const float*)d_in[13];
    const float* bhh_f  = (const float*)d_in[14];
    const float* Wih_b  = (const float*)d_in[15];
    const float* Whh_b  = (const float*)d_in[16];
    const float* bih_b  = (const float*)d_in[17];
    const float* bhh_b  = (const float*)d_in[18];
    const float* conv_w = (const float*)d_in[19];
    const float* conv_b = (const float*)d_in[20];
    const float* fcp_w  = (const float*)d_in[21];
    const float* fcp_b  = (const float*)d_in[22];
    const float* fc1_w  = (const float*)d_in[23];
    const float* fc1_b  = (const float*)d_in[24];
    const float* fc2_w  = (const float*)d_in[25];
    const float* fc2_b  = (const float*)d_in[26];
    const float* out_w  = (const float*)d_in[27];
    const float* out_b  = (const float*)d_in[28];
    float* out = (float*)d_out;
    (void)n_in; (void)in_sizes; (void)out_size;

    // ---------- workspace layout ----------
    char* ws = (char*)d_ws;
    size_t o = 0;
    auto alloc = [&](size_t bytes) {
        char* p = ws + o;
        o = (o + bytes + 255) & ~(size_t)255;
        return p;
    };
    constexpr size_t HALF = (size_t)HH * NNP * CCP * 2; // 48.1 MB (one sliced matrix)
    // Union region: protein {hcat,proj26,convout,wT,hcatT,T} -> {xl|xr} -> {hw|g}
    char* region = (char*)alloc(2 * HALF);
    __hip_bfloat16* xl_sl = (__hip_bfloat16*)region;
    __hip_bfloat16* xr_sl = (__hip_bfloat16*)(region + HALF);
    __hip_bfloat16* hw_sl = (__hip_bfloat16*)region;          // after xl dead
    __hip_bfloat16* g_sl  = (__hip_bfloat16*)(region + HALF); // after xr dead
    // protein-phase sub-layout inside the union region
    char* rp = region;
    auto palloc = [&](size_t bytes) {
        char* p = rp;
        rp += (bytes + 255) & ~(size_t)255;
        return p;
    };
    float* hcat    = (float*)palloc((size_t)BB * SEQ * 128 * 4);   // 32.8 MB
    float* proj26  = (float*)palloc(2 * 26 * 256 * 4);             // 53 KB
    float* convout = (float*)palloc((size_t)BB * 3872 * 4);        // 1 MB
    __hip_bfloat16* wT = (__hip_bfloat16*)palloc((size_t)256 * SEQ * 2);        // 0.5 MB
    unsigned short* hcatT = (unsigned short*)palloc((size_t)BB * 128 * SEQ * 2); // 16.4 MB
    float* T = (float*)palloc((size_t)BB * 128 * 256 * 4);         // 8.4 MB
    // Persistent buffers
    __hip_bfloat16* h_bf  = (__hip_bfloat16*)alloc((size_t)NNP * DDP * 2); // dense padded (glds A)
    __hip_bfloat16* x_bf  = (__hip_bfloat16*)alloc((size_t)NNP * KXP * 2);
    __hip_bfloat16* wl_t  = (__hip_bfloat16*)alloc((size_t)NBP * KXP * 2);
    __hip_bfloat16* wr_t  = (__hip_bfloat16*)alloc((size_t)NBP * KXP * 2);
    __hip_bfloat16* gcw_t = (__hip_bfloat16*)alloc((size_t)NBP * DDP * 2);
    float* att_p  = (float*)alloc((size_t)HH * CCP * 4);
    float* fcp_wt = (float*)alloc((size_t)3872 * 128 * 4);
    float* fc1_wt = (float*)alloc((size_t)COMBD * 1024 * 4);
    float* fc2_wt = (float*)alloc((size_t)1024 * 512 * 4);
    float* out_wt = (float*)alloc((size_t)512 * 4);
    float* logit    = (float*)alloc((size_t)ET * HH * 4); // head-major; alpha in place
    int*   csr_src  = (int*)alloc((size_t)ET * 4);
    int*   csr_dst  = (int*)alloc((size_t)ET * 4);
    int*   deg      = (int*)alloc((size_t)NN * 4);
    int*   cursor   = (int*)alloc((size_t)NN * 4);
    int*   offs     = (int*)alloc((size_t)(NN + 1) * 4);
    float* dinv     = (float*)alloc((size_t)NN * 4);
    int*   gstart   = (int*)alloc(64 * 4);
    int*   gend     = (int*)alloc(64 * 4);
    float* pmax     = (float*)alloc((size_t)BB * DD * 4);
    float* psum     = (float*)alloc((size_t)BB * DD * 4);
    float* comb     = (float*)alloc((size_t)BB * COMBD * 4);
    float* h1       = (float*)alloc((size_t)BB * 1024 * 4);
    float* h2       = (float*)alloc((size_t)BB * 512 * 4);
    if (o > ws_size) return;  // diagnostic: insufficient workspace -> no launches

    // zero scratch that is accumulated into
    hipMemsetAsync(deg, 0, (size_t)NN * 4, stream);
    hipMemsetAsync(cursor, 0, (size_t)NN * 4, stream);
    hipMemsetAsync(gstart, 0, 64 * 4, stream);
    hipMemsetAsync(gend, 0, 64 * 4, stream);
    hipMemsetAsync(pmax, 0, (size_t)BB * DD * 4, stream);
    hipMemsetAsync(psum, 0, (size_t)BB * DD * 4, stream);

    // ---------- protein branch (uses the union region first) ----------
    {
        dim3 grid(2, 26);
        proj26_kernel<<<grid, 256, 0, stream>>>(emb, Wih_f, bih_f, bhh_f, Wih_b, bih_b, bhh_b, proj26);
    }
    {
        dim3 grid(SEQ, 2);
        lstm_kernel<<<grid, 256, 0, stream>>>(target, proj26, Whh_f, Whh_b, hcat);
    }
    // conv as MFMA GEMM (K=1000 not %32 -> legacy staging kernel)
    {
        dim3 grid(4, 32, BB);
        transpose_hcat<<<grid, 256, 0, stream>>>(hcat, hcatT);
    }
    reshape_convw<<<(256 * SEQ + 255) / 256, 256, 0, stream>>>(conv_w, wT);
    {
        dim3 grid(2, 64);
        gemm_bf16_mfma<<<grid, 256, 0, stream>>>((const __hip_bfloat16*)hcatT, wT, T,
                                                 BB * 128, 256, SEQ, 256);
    }
    conv_finalize<<<(BB * 32 * 121 + 255) / 256, 256, 0, stream>>>(T, conv_b, convout);
    transpose_f32<<<(3872 * 128 + 255) / 256, 256, 0, stream>>>(fcp_w, fcp_wt, 3872, 128);
    gemm_skinny<0><<<(BB * 128 + 3) / 4, 256, 0, stream>>>(convout, fcp_wt, fcp_b,
                                                           comb + 2 * DD, BB, 128, 3872, COMBD);

    // ---------- conversions / padding ----------
    pad_x<<<(NNP * KXP + 255) / 256, 256, 0, stream>>>(x, x_bf);
    pad_wT<<<(NBP * KXP + 255) / 256, 256, 0, stream>>>(Wl, wl_t);
    pad_wT<<<(NBP * KXP + 255) / 256, 256, 0, stream>>>(Wr, wr_t);
    pad_gcwT<<<(NBP * DDP + 255) / 256, 256, 0, stream>>>(gcn_w, gcw_t);
    pad_att<<<(HH * CCP + 255) / 256, 256, 0, stream>>>(att, att_p);
    transpose_f32<<<(COMBD * 1024 + 255) / 256, 256, 0, stream>>>(fc1_w, fc1_wt, COMBD, 1024);
    transpose_f32<<<(1024 * 512 + 255) / 256, 256, 0, stream>>>(fc2_w, fc2_wt, 1024, 512);
    transpose_f32<<<(512 + 255) / 256, 256, 0, stream>>>(out_w, out_wt, 512, 1);

    // ---------- graph branch ----------
    dim3 ggrid((DD + 127) / 128, NNP / 128);   // 7 x 235
    gemm_glds_sl<<<ggrid, 256, 0, stream>>>(x_bf, wl_t, xl_sl, NN, DD, KXP);
    gemm_glds_sl<<<ggrid, 256, 0, stream>>>(x_bf, wr_t, xr_sl, NN, DD, KXP);
    zero_pads<<<(NN * HH + 255) / 256, 256, 0, stream>>>((unsigned int*)xl_sl, (unsigned int*)xr_sl);
    // CSR
    deg_count<<<(ET + 255) / 256, 256, 0, stream>>>(ei, deg);
    scan_kernel<<<1, 1024, 0, stream>>>(deg, offs);
    csr_fill<<<(ET + 255) / 256, 256, 0, stream>>>(ei, offs, cursor, csr_src, csr_dst);
    dinv_kernel<<<(NN + 255) / 256, 256, 0, stream>>>(deg, dinv);
    // GATv2: head-pure blocks for L2 locality on the xl gather
    {
        dim3 grid((ET + 255) / 256, HH);
        gat_logits<<<grid, 256, 0, stream>>>((const unsigned short*)xl_sl,
                                             (const unsigned short*)xr_sl,
                                             att_p, csr_src, csr_dst, logit);
    }
    gat_softmax<<<(NN * HH + 255) / 256, 256, 0, stream>>>(offs, logit);
    gat_aggregate<<<NN, 256, 0, stream>>>(offs, csr_src, logit,
                                          (const unsigned int*)xl_sl, gat_b,
                                          (unsigned int*)h_bf);
    // GCN: hw = h @ gcn_w^T via glds GEMM -> head-sliced hw
    {
        dim3 g2((DD + 127) / 128, NNP / 128);
        gemm_glds_sl<<<g2, 256, 0, stream>>>(h_bf, gcw_t, hw_sl, NN, DD, DDP);
    }
    gcn_aggregate<<<NN, 256, 0, stream>>>(offs, csr_src, dinv,
                                          (const unsigned int*)hw_sl, gcn_b,
                                          (unsigned int*)g_sl);
    // pooling -> comb[:, 0:1560]
    graph_ranges<<<(NN + 255) / 256, 256, 0, stream>>>(batch, gstart, gend);
    pool_partial<<<(NN + PCHUNK - 1) / PCHUNK, 256, 0, stream>>>((const unsigned int*)g_sl,
                                                                 batch, pmax, psum);
    pool_finalize<<<(BB * DD + 255) / 256, 256, 0, stream>>>(pmax, psum, gstart, gend, comb);

    // ---------- combined head ----------
    gemm_skinny<1><<<(BB * 1024 + 3) / 4, 256, 0, stream>>>(comb, fc1_wt, fc1_b, h1,
                                                            BB, 1024, COMBD, 1024);
    gemm_skinny<1><<<(BB * 512 + 3) / 4, 256, 0, stream>>>(h1, fc2_wt, fc2_b, h2,
                                                           BB, 512, 1024, 512);
    gemm_skinny<0><<<(BB + 3) / 4, 256, 0, stream>>>(h2, out_wt, out_b, out,
                                                     BB, 1, 512, 1);
}

// Round 13
// 863.867 us; speedup vs baseline: 1.0151x; 1.0151x over previous
//
#include <hip/hip_runtime.h>
#include <hip/hip_bf16.h>
#include <math.h>

// Problem constants (fixed by setup_inputs)
static constexpr int NN   = 30000;   // nodes
static constexpr int EE   = 240000;  // edges (before self loops)
static constexpr int ET   = EE + NN; // edges incl self loops
static constexpr int BB   = 64;      // graphs
static constexpr int HH   = 10;      // heads
static constexpr int CC   = 78;      // per-head dim
static constexpr int CCP  = 80;      // padded per-head dim (16B-aligned slices)
static constexpr int DD   = HH * CC; // 780
static constexpr int DDP  = HH * CCP;// 800 (padded row)
static constexpr int NNP  = 30080;   // nodes padded to x128 (glds GEMM M)
static constexpr int KXP  = 96;      // x K padded to x32
static constexpr int NBP  = 896;     // B^T rows padded to x128
static constexpr int SEQ  = 1000;
static constexpr int EMB  = 128;
static constexpr int LH   = 64;
static constexpr int COMBD = 2 * DD + 128; // 1688
static constexpr int PCHUNK = 64;    // nodes per pool_partial block
static constexpr int USL  = CCP / 2;            // 40 uints per head-row
static constexpr size_t SLICE_U = (size_t)NNP * USL; // uints per head slice

typedef __attribute__((ext_vector_type(8))) short short8;
typedef __attribute__((ext_vector_type(4))) float f32x4;

__device__ __forceinline__ float bflo(unsigned int u) {
    return __uint_as_float(u << 16);
}
__device__ __forceinline__ float bfhi(unsigned int u) {
    return __uint_as_float(u & 0xffff0000u);
}
__device__ __forceinline__ unsigned int pack2bf(float x, float y) {
    __hip_bfloat16 bx = __float2bfloat16(x), by = __float2bfloat16(y);
    unsigned short ux = *reinterpret_cast<unsigned short*>(&bx);
    unsigned short uy = *reinterpret_cast<unsigned short*>(&by);
    return (unsigned int)ux | ((unsigned int)uy << 16);
}
__device__ __forceinline__ float fast_sigmoid(float x) {
    return __builtin_amdgcn_rcpf(1.f + __expf(-x));
}
__device__ __forceinline__ float fast_tanh(float x) {
    float e = __expf(2.f * x);
    return 1.f - 2.f * __builtin_amdgcn_rcpf(e + 1.f);
}
__device__ __forceinline__ void glds16(const unsigned short* g, unsigned short* l) {
    __builtin_amdgcn_global_load_lds(
        (const __attribute__((address_space(1))) unsigned int*)g,
        (__attribute__((address_space(3))) unsigned int*)l, 16, 0, 0);
}

// ======== glds MFMA GEMM, SLICED epilogue: C[col/78][row][col%78] bf16 ========
// A [Mp,Kp] row-major bf16 (pads allocated, K-pads zero), Bt [Np,Kp].
// Kp%32==0, grid covers Mp/128 x Np/128. Output written only row<M, col<N.
__global__ __launch_bounds__(256) void gemm_glds_sl(const __hip_bfloat16* __restrict__ A,
                                                    const __hip_bfloat16* __restrict__ Bt,
                                                    __hip_bfloat16* __restrict__ C,
                                                    int M, int N, int Kp) {
    __shared__ unsigned short As[128 * 32];
    __shared__ unsigned short Bs[128 * 32];
    const int tid  = threadIdx.x;
    const int lane = tid & 63, wid = tid >> 6;
    const int wr = wid >> 1, wc = wid & 1;
    const int l15 = lane & 15, l4 = lane >> 4;
    int l = blockIdx.y * gridDim.x + blockIdx.x;
    {   // bijective XCD swizzle (m204)
        int nwg = gridDim.x * gridDim.y;
        int q = nwg >> 3, r = nwg & 7;
        int xcd = l & 7, idx = l >> 3;
        l = (xcd < r) ? (xcd * (q + 1) + idx) : (r * (q + 1) + (xcd - r) * q + idx);
    }
    const int bm = (l / gridDim.x) * 128;
    const int bn = (l % gridDim.x) * 128;
    const unsigned short* Au = (const unsigned short*)A;
    const unsigned short* Bu = (const unsigned short*)Bt;
    const int lrow = lane >> 2, lseg = (lane & 3) * 8;

    f32x4 acc[4][4];
#pragma unroll
    for (int m = 0; m < 4; ++m)
#pragma unroll
        for (int n = 0; n < 4; ++n) acc[m][n] = (f32x4){0.f, 0.f, 0.f, 0.f};

    for (int k0 = 0; k0 < Kp; k0 += 32) {
#pragma unroll
        for (int c = 0; c < 2; ++c) {
            int rbase = wid * 32 + c * 16;
            glds16(Au + (size_t)(bm + rbase + lrow) * Kp + k0 + lseg, &As[rbase * 32]);
            glds16(Bu + (size_t)(bn + rbase + lrow) * Kp + k0 + lseg, &Bs[rbase * 32]);
        }
        __syncthreads();
        short8 a[4], b[4];
#pragma unroll
        for (int m = 0; m < 4; ++m)
            a[m] = *reinterpret_cast<const short8*>(&As[(wr * 64 + m * 16 + l15) * 32 + l4 * 8]);
#pragma unroll
        for (int n = 0; n < 4; ++n)
            b[n] = *reinterpret_cast<const short8*>(&Bs[(wc * 64 + n * 16 + l15) * 32 + l4 * 8]);
#pragma unroll
        for (int m = 0; m < 4; ++m)
#pragma unroll
            for (int n = 0; n < 4; ++n)
                acc[m][n] = __builtin_amdgcn_mfma_f32_16x16x32_bf16(a[m], b[n], acc[m][n], 0, 0, 0);
        __syncthreads();
    }
#pragma unroll
    for (int m = 0; m < 4; ++m)
#pragma unroll
        for (int n = 0; n < 4; ++n)
#pragma unroll
            for (int r = 0; r < 4; ++r) {
                int row = bm + wr * 64 + m * 16 + l4 * 4 + r;
                int col = bn + wc * 64 + n * 16 + l15;
                if (row < M && col < N) {
                    int sl = col / CC, c = col % CC;
                    C[(size_t)sl * NNP * CCP + (size_t)row * CCP + c] =
                        __float2bfloat16(acc[m][n][r]);
                }
            }
}

// ======== legacy VGPR-staging MFMA GEMM (conv GEMM: K=1000 not %32) ========
__global__ __launch_bounds__(256) void gemm_bf16_mfma(const __hip_bfloat16* __restrict__ A,
                                                      const __hip_bfloat16* __restrict__ Bt,
                                                      float* __restrict__ C,
                                                      int M, int N, int K, int ldc) {
    constexpr int LDS_S = 40;
    __shared__ unsigned short As[128 * LDS_S];
    __shared__ unsigned short Bs[128 * LDS_S];
    const int tid  = threadIdx.x;
    const int lane = tid & 63, wid = tid >> 6;
    const int wr = wid >> 1, wc = wid & 1;
    const int l15 = lane & 15, l4 = lane >> 4;
    int l = blockIdx.y * gridDim.x + blockIdx.x;
    {
        int nwg = gridDim.x * gridDim.y;
        int q = nwg >> 3, r = nwg & 7;
        int xcd = l & 7, idx = l >> 3;
        l = (xcd < r) ? (xcd * (q + 1) + idx) : (r * (q + 1) + (xcd - r) * q + idx);
    }
    const int bm = (l / gridDim.x) * 128;
    const int bn = (l % gridDim.x) * 128;
    const int tr = tid >> 2, tc = (tid & 3) * 8;

    const unsigned short* Au = (const unsigned short*)A;
    const unsigned short* Bu = (const unsigned short*)Bt;

    f32x4 acc[4][4];
#pragma unroll
    for (int m = 0; m < 4; ++m)
#pragma unroll
        for (int n = 0; n < 4; ++n) acc[m][n] = (f32x4){0.f, 0.f, 0.f, 0.f};

    for (int k0 = 0; k0 < K; k0 += 32) {
#pragma unroll
        for (int half = 0; half < 2; ++half) {
            int row = tr + half * 64;
            { // A tile
                int grow = bm + row;
                short8 sv;
                if (grow < M && k0 + tc + 8 <= K) {
                    const unsigned int* p = (const unsigned int*)(Au + (size_t)grow * K + k0 + tc);
#pragma unroll
                    for (int j = 0; j < 4; ++j) {
                        unsigned int u = p[j];
                        sv[2 * j]     = (short)(u & 0xffffu);
                        sv[2 * j + 1] = (short)(u >> 16);
                    }
                } else {
#pragma unroll
                    for (int j = 0; j < 8; ++j) {
                        int gk = k0 + tc + j;
                        sv[j] = (grow < M && gk < K) ? (short)Au[(size_t)grow * K + gk] : (short)0;
                    }
                }
                *reinterpret_cast<short8*>(&As[row * LDS_S + tc]) = sv;
            }
            { // B^T tile
                int grow = bn + row;
                short8 sv;
                if (grow < N && k0 + tc + 8 <= K) {
                    const unsigned int* p = (const unsigned int*)(Bu + (size_t)grow * K + k0 + tc);
#pragma unroll
                    for (int j = 0; j < 4; ++j) {
                        unsigned int u = p[j];
                        sv[2 * j]     = (short)(u & 0xffffu);
                        sv[2 * j + 1] = (short)(u >> 16);
                    }
                } else {
#pragma unroll
                    for (int j = 0; j < 8; ++j) {
                        int gk = k0 + tc + j;
                        sv[j] = (grow < N && gk < K) ? (short)Bu[(size_t)grow * K + gk] : (short)0;
                    }
                }
                *reinterpret_cast<short8*>(&Bs[row * LDS_S + tc]) = sv;
            }
        }
        __syncthreads();
        short8 a[4], b[4];
#pragma unroll
        for (int m = 0; m < 4; ++m)
            a[m] = *reinterpret_cast<const short8*>(&As[(wr * 64 + m * 16 + l15) * LDS_S + l4 * 8]);
#pragma unroll
        for (int n = 0; n < 4; ++n)
            b[n] = *reinterpret_cast<const short8*>(&Bs[(wc * 64 + n * 16 + l15) * LDS_S + l4 * 8]);
#pragma unroll
        for (int m = 0; m < 4; ++m)
#pragma unroll
            for (int n = 0; n < 4; ++n)
                acc[m][n] = __builtin_amdgcn_mfma_f32_16x16x32_bf16(a[m], b[n], acc[m][n], 0, 0, 0);
        __syncthreads();
    }
#pragma unroll
    for (int m = 0; m < 4; ++m)
#pragma unroll
        for (int n = 0; n < 4; ++n)
#pragma unroll
            for (int r = 0; r < 4; ++r) {
                int row = bm + wr * 64 + m * 16 + l4 * 4 + r;
                int col = bn + wc * 64 + n * 16 + l15;
                if (row < M && col < N)
                    C[(size_t)row * ldc + col] = acc[m][n][r];
            }
}

// ---------------- conversions / padding ----------------
__global__ void pad_x(const float* __restrict__ x, __hip_bfloat16* __restrict__ xp) {
    int idx = blockIdx.x * blockDim.x + threadIdx.x;
    if (idx >= NNP * KXP) return;
    int r = idx / KXP, c = idx % KXP;
    float v = (r < NN && c < CC) ? x[(size_t)r * CC + c] : 0.f;
    xp[idx] = __float2bfloat16(v);
}

__global__ void pad_wT(const float* __restrict__ w, __hip_bfloat16* __restrict__ wt) {
    int idx = blockIdx.x * blockDim.x + threadIdx.x;
    if (idx >= NBP * KXP) return;
    int n = idx / KXP, k = idx % KXP;
    float v = (n < DD && k < CC) ? w[(size_t)k * DD + n] : 0.f;
    wt[idx] = __float2bfloat16(v);
}

// gcn_w [DD][DD] -> wt [NBP][DDP] with head-padded K map (matches dense h rows)
__global__ void pad_gcwT(const float* __restrict__ w, __hip_bfloat16* __restrict__ wt) {
    int idx = blockIdx.x * blockDim.x + threadIdx.x;
    if (idx >= NBP * DDP) return;
    int n = idx / DDP, kp = idx % DDP;
    int kc = kp % CCP;
    int k = (kp / CCP) * CC + kc;
    float v = (n < DD && kc < CC) ? w[(size_t)k * DD + n] : 0.f;
    wt[idx] = __float2bfloat16(v);
}

__global__ void transpose_f32(const float* __restrict__ in, float* __restrict__ out,
                              int Kdim, int Ndim) {
    int idx = blockIdx.x * blockDim.x + threadIdx.x;
    if (idx >= Kdim * Ndim) return;
    int n = idx / Kdim, k = idx % Kdim;
    out[idx] = in[(size_t)k * Ndim + n];
}

__global__ void pad_att(const float* __restrict__ att, float* __restrict__ att_p) {
    int idx = blockIdx.x * blockDim.x + threadIdx.x;
    if (idx >= HH * CCP) return;
    int h = idx / CCP, c = idx % CCP;
    att_p[idx] = (c < CC) ? att[h * CC + c] : 0.f;
}

// zero pad lanes (c=78,79) of each head slice, rows < NN, both matrices
__global__ void zero_pads(unsigned int* __restrict__ a, unsigned int* __restrict__ b) {
    int idx = blockIdx.x * blockDim.x + threadIdx.x;
    if (idx >= NN * HH) return;
    int n = idx / HH, h = idx % HH;
    size_t p = (size_t)h * SLICE_U + (size_t)n * USL + (USL - 1);
    a[p] = 0u;
    b[p] = 0u;
}

// ------------- skinny GEMM: wave-per-output split-K. Bt is [N][K]. -------------
template <int ACT>
__global__ __launch_bounds__(256) void gemm_skinny(const float* __restrict__ A,
                                                   const float* __restrict__ Bt,
                                                   const float* __restrict__ bias,
                                                   float* __restrict__ C,
                                                   int M, int N, int K, int ldc) {
    int oidx = blockIdx.x * 4 + (threadIdx.x >> 6);
    int lane = threadIdx.x & 63;
    if (oidx >= M * N) return;
    int row = oidx / N, col = oidx % N;
    const float4* a = (const float4*)(A + (size_t)row * K);
    const float4* b = (const float4*)(Bt + (size_t)col * K);
    int K4 = K >> 2;
    float s = 0.f;
    for (int i = lane; i < K4; i += 64) {
        float4 x = a[i], y = b[i];
        s += x.x * y.x + x.y * y.y + x.z * y.z + x.w * y.w;
    }
#pragma unroll
    for (int off = 32; off; off >>= 1) s += __shfl_xor(s, off);
    if (lane == 0) {
        s += bias[col];
        if (ACT == 1) s = fmaxf(s, 0.f);
        C[(size_t)row * ldc + col] = s;
    }
}

// ---------------- CSR construction ----------------
__global__ void deg_count(const int* __restrict__ ei, int* __restrict__ deg) {
    int e = blockIdx.x * blockDim.x + threadIdx.x;
    if (e >= ET) return;
    int d = (e < EE) ? ei[EE + e] : (e - EE);
    atomicAdd(&deg[d], 1);
}

__global__ __launch_bounds__(1024) void scan_kernel(const int* __restrict__ deg,
                                                    int* __restrict__ offs) {
    __shared__ int lds[1024];
    int tid = threadIdx.x;
    const int chunk = (NN + 1023) / 1024;
    int base = tid * chunk;
    int s = 0;
    for (int i = 0; i < chunk; ++i) {
        int idx = base + i;
        if (idx < NN) s += deg[idx];
    }
    lds[tid] = s;
    __syncthreads();
    for (int d = 1; d < 1024; d <<= 1) {
        int v = (tid >= d) ? lds[tid - d] : 0;
        __syncthreads();
        lds[tid] += v;
        __syncthreads();
    }
    int run = (tid == 0) ? 0 : lds[tid - 1];
    for (int i = 0; i < chunk; ++i) {
        int idx = base + i;
        if (idx < NN) { offs[idx] = run; run += deg[idx]; }
    }
    if (tid == 1023) offs[NN] = lds[1023];
}

__global__ void csr_fill(const int* __restrict__ ei, const int* __restrict__ offs,
                         int* __restrict__ cursor, int* __restrict__ csr_src,
                         int* __restrict__ csr_dst) {
    int e = blockIdx.x * blockDim.x + threadIdx.x;
    if (e >= ET) return;
    int s = (e < EE) ? ei[e] : (e - EE);
    int d = (e < EE) ? ei[EE + e] : (e - EE);
    int pos = atomicAdd(&cursor[d], 1);
    int slot = offs[d] + pos;
    csr_src[slot] = s;
    csr_dst[slot] = d;
}

__global__ void dinv_kernel(const int* __restrict__ deg, float* __restrict__ dinv) {
    int n = blockIdx.x * blockDim.x + threadIdx.x;
    if (n >= NN) return;
    float dg = (float)deg[n];
    dinv[n] = (dg > 0.f) ? 1.f / sqrtf(dg) : 0.f;
}

// ---------------- GATv2 (head-sliced bf16 gathers) ----------------
__device__ __forceinline__ float dot2lr(unsigned int a, unsigned int b, float w0, float w1) {
    float v0 = bflo(a) + bflo(b);
    float v1 = bfhi(a) + bfhi(b);
    v0 = (v0 > 0.f) ? v0 : 0.2f * v0;
    v1 = (v1 > 0.f) ? v1 : 0.2f * v1;
    return w0 * v0 + w1 * v1;
}

// grid: (ceil(ET/256), HH) -> head-pure blocks, per-XCD working set ~ one slice
__global__ void gat_logits(const unsigned short* __restrict__ xl_sl,
                           const unsigned short* __restrict__ xr_sl,
                           const float* __restrict__ att_p, const int* __restrict__ csr_src,
                           const int* __restrict__ csr_dst, float* __restrict__ logit_hm) {
    int i = blockIdx.x * blockDim.x + threadIdx.x;
    int h = blockIdx.y;
    if (i >= ET) return;
    int s = csr_src[i], d = csr_dst[i];
    const uint4* pl = (const uint4*)(xl_sl + (size_t)h * NNP * CCP + (size_t)s * CCP);
    const uint4* pr = (const uint4*)(xr_sl + (size_t)h * NNP * CCP + (size_t)d * CCP);
    const float* pa = att_p + h * CCP;
    float acc = 0.f;
#pragma unroll
    for (int q = 0; q < CCP / 8; ++q) {
        uint4 a = pl[q], b = pr[q];
        const float* p8 = pa + q * 8;
        acc += dot2lr(a.x, b.x, p8[0], p8[1]);
        acc += dot2lr(a.y, b.y, p8[2], p8[3]);
        acc += dot2lr(a.z, b.z, p8[4], p8[5]);
        acc += dot2lr(a.w, b.w, p8[6], p8[7]);
    }
    logit_hm[(size_t)h * ET + i] = acc;
}

__global__ void gat_softmax(const int* __restrict__ offs, float* __restrict__ logit_hm) {
    int idx = blockIdx.x * blockDim.x + threadIdx.x;
    if (idx >= NN * HH) return;
    int n = idx / HH, h = idx % HH;
    int i0 = offs[n], i1 = offs[n + 1];
    float* lg = logit_hm + (size_t)h * ET;
    float m = -1e30f;
    for (int i = i0; i < i1; ++i) m = fmaxf(m, lg[i]);
    float den = 0.f;
    for (int i = i0; i < i1; ++i) {
        float e = __expf(lg[i] - m);
        lg[i] = e;
        den += e;
    }
    float inv = __builtin_amdgcn_rcpf(den);
    for (int i = i0; i < i1; ++i) lg[i] *= inv;
}

// reads head-sliced xl (uint lanes), writes DENSE-padded h rows (pads zero)
__global__ __launch_bounds__(256) void gat_aggregate(const int* __restrict__ offs,
                                                     const int* __restrict__ csr_src,
                                                     const float* __restrict__ alpha_hm,
                                                     const unsigned int* __restrict__ xl_sl,
                                                     const float* __restrict__ gat_b,
                                                     unsigned int* __restrict__ hout) {
    int n = blockIdx.x;
    int tid = threadIdx.x;
    int i0 = offs[n], i1 = offs[n + 1];
    const int U = DDP / 2;  // 400
    int u0 = tid, u1 = tid + 256;
    bool v1 = (u1 < U);
    int h0 = u0 / USL, c0 = u0 % USL;
    int h1 = v1 ? u1 / USL : 0, c1 = v1 ? u1 % USL : 0;
    const unsigned int* s0 = xl_sl + (size_t)h0 * SLICE_U + c0;
    const unsigned int* s1 = xl_sl + (size_t)h1 * SLICE_U + c1;
    const float* a0p = alpha_hm + (size_t)h0 * ET;
    const float* a1p = alpha_hm + (size_t)h1 * ET;
    float lo0 = 0.f, hi0 = 0.f, lo1 = 0.f, hi1 = 0.f;
    for (int i = i0; i < i1; ++i) {
        int src = csr_src[i];
        unsigned int w0 = s0[(size_t)src * USL];
        float p0 = a0p[i];
        lo0 += p0 * bflo(w0);
        hi0 += p0 * bfhi(w0);
        if (v1) {
            unsigned int w1 = s1[(size_t)src * USL];
            float p1 = a1p[i];
            lo1 += p1 * bflo(w1);
            hi1 += p1 * bfhi(w1);
        }
    }
    unsigned int ov0 = 0u, ov1 = 0u;
    if (c0 != USL - 1) {
        int d = h0 * CC + 2 * c0;
        float x = lo0 + gat_b[d];     x = (x > 0.f) ? x : __expf(x) - 1.f;
        float y = hi0 + gat_b[d + 1]; y = (y > 0.f) ? y : __expf(y) - 1.f;
        ov0 = pack2bf(x, y);
    }
    hout[(size_t)n * U + u0] = ov0;
    if (v1) {
        if (c1 != USL - 1) {
            int d = h1 * CC + 2 * c1;
            float x = lo1 + gat_b[d];     x = (x > 0.f) ? x : __expf(x) - 1.f;
            float y = hi1 + gat_b[d + 1]; y = (y > 0.f) ? y : __expf(y) - 1.f;
            ov1 = pack2bf(x, y);
        }
        hout[(size_t)n * U + u1] = ov1;
    }
}

// ------------- GCN aggregation (head-sliced in/out, uint lanes) -------------
__global__ __launch_bounds__(256) void gcn_aggregate(const int* __restrict__ offs,
                                                     const int* __restrict__ csr_src,
                                                     const float* __restrict__ dinv,
                                                     const unsigned int* __restrict__ hw_sl,
                                                     const float* __restrict__ gcn_b,
                                                     unsigned int* __restrict__ g_sl) {
    int n = blockIdx.x;
    int tid = threadIdx.x;
    float din = dinv[n];
    int i0 = offs[n], i1 = offs[n + 1];
    const int U = DDP / 2;
    int u0 = tid, u1 = tid + 256;
    bool v1 = (u1 < U);
    int h0 = u0 / USL, c0 = u0 % USL;
    int h1 = v1 ? u1 / USL : 0, c1 = v1 ? u1 % USL : 0;
    const unsigned int* s0 = hw_sl + (size_t)h0 * SLICE_U + c0;
    const unsigned int* s1 = hw_sl + (size_t)h1 * SLICE_U + c1;
    float lo0 = 0.f, hi0 = 0.f, lo1 = 0.f, hi1 = 0.f;
    for (int i = i0; i < i1; ++i) {
        int src = csr_src[i];
        float w = dinv[src] * din;
        unsigned int w0 = s0[(size_t)src * USL];
        lo0 += w * bflo(w0);
        hi0 += w * bfhi(w0);
        if (v1) {
            unsigned int w1 = s1[(size_t)src * USL];
            lo1 += w * bflo(w1);
            hi1 += w * bfhi(w1);
        }
    }
    if (c0 != USL - 1) {
        int d = h0 * CC + 2 * c0;
        float x = fmaxf(lo0 + gcn_b[d], 0.f);
        float y = fmaxf(hi0 + gcn_b[d + 1], 0.f);
        g_sl[(size_t)h0 * SLICE_U + (size_t)n * USL + c0] = pack2bf(x, y);
    }
    if (v1 && c1 != USL - 1) {
        int d = h1 * CC + 2 * c1;
        float x = fmaxf(lo1 + gcn_b[d], 0.f);
        float y = fmaxf(hi1 + gcn_b[d + 1], 0.f);
        g_sl[(size_t)h1 * SLICE_U + (size_t)n * USL + c1] = pack2bf(x, y);
    }
}

// ---------------- pooling ----------------
__global__ void graph_ranges(const int* __restrict__ batch, int* __restrict__ gstart,
                             int* __restrict__ gend) {
    int n = blockIdx.x * blockDim.x + threadIdx.x;
    if (n >= NN) return;
    int b = batch[n];
    if (n == 0 || batch[n - 1] != b) gstart[b] = n;
    if (n == NN - 1 || batch[n + 1] != b) gend[b] = n + 1;
}

// g head-sliced (uint lanes). g >= 0 (ReLU): atomicMax on uint bits exact.
__global__ __launch_bounds__(256) void pool_partial(const unsigned int* __restrict__ g_sl,
                                                    const int* __restrict__ batch,
                                                    float* __restrict__ pmax,
                                                    float* __restrict__ psum) {
    int chunk0 = blockIdx.x * PCHUNK;
    int tid = threadIdx.x;
    __shared__ int bsh[PCHUNK];
    for (int i = tid; i < PCHUNK; i += 256) {
        int n = chunk0 + i;
        bsh[i] = (n < NN) ? batch[n] : -1;
    }
    __syncthreads();
    const int U = DDP / 2;
    int u0 = tid, u1 = tid + 256;
    bool v1 = (u1 < U);
    int h0 = u0 / USL, c0 = u0 % USL;
    int h1 = v1 ? u1 / USL : 0, c1 = v1 ? u1 % USL : 0;
    const unsigned int* s0 = g_sl + (size_t)h0 * SLICE_U + c0;
    const unsigned int* s1 = g_sl + (size_t)h1 * SLICE_U + c1;
    float mA = 0.f, mB = 0.f, mC = 0.f, mD = 0.f;
    float sA = 0.f, sB = 0.f, sC = 0.f, sD = 0.f;
    int curb = bsh[0];
    auto flush = [&](int b) {
        if (b >= 0) {
            if (c0 != USL - 1) {
                int d = h0 * CC + 2 * c0;
                atomicMax((unsigned int*)&pmax[(size_t)b * DD + d], __float_as_uint(mA));
                atomicAdd(&psum[(size_t)b * DD + d], sA);
                atomicMax((unsigned int*)&pmax[(size_t)b * DD + d + 1], __float_as_uint(mB));
                atomicAdd(&psum[(size_t)b * DD + d + 1], sB);
            }
            if (v1 && c1 != USL - 1) {
                int d = h1 * CC + 2 * c1;
                atomicMax((unsigned int*)&pmax[(size_t)b * DD + d], __float_as_uint(mC));
                atomicAdd(&psum[(size_t)b * DD + d], sC);
                atomicMax((unsigned int*)&pmax[(size_t)b * DD + d + 1], __float_as_uint(mD));
                atomicAdd(&psum[(size_t)b * DD + d + 1], sD);
            }
        }
        mA = mB = mC = mD = 0.f;
        sA = sB = sC = sD = 0.f;
    };
    for (int i = 0; i < PCHUNK; ++i) {
        int n = chunk0 + i;
        if (n >= NN) break;
        int b = bsh[i];
        if (b != curb) { flush(curb); curb = b; }
        unsigned int w0 = s0[(size_t)n * USL];
        float x = bflo(w0), y = bfhi(w0);
        mA = fmaxf(mA, x); sA += x;
        mB = fmaxf(mB, y); sB += y;
        if (v1) {
            unsigned int w1 = s1[(size_t)n * USL];
            float z = bflo(w1), t = bfhi(w1);
            mC = fmaxf(mC, z); sC += z;
            mD = fmaxf(mD, t); sD += t;
        }
    }
    flush(curb);
}

__global__ void pool_finalize(const float* __restrict__ pmax, const float* __restrict__ psum,
                              const int* __restrict__ gstart, const int* __restrict__ gend,
                              float* __restrict__ comb) {
    int idx = blockIdx.x * blockDim.x + threadIdx.x;
    if (idx >= BB * DD) return;
    int b = idx / DD, d = idx % DD;
    float cnt = fmaxf((float)(gend[b] - gstart[b]), 1.f);
    comb[(size_t)b * COMBD + d] = pmax[idx];
    comb[(size_t)b * COMBD + DD + d] = psum[idx] / cnt;
}

// ---------------- protein branch ----------------
__global__ void proj26_kernel(const float* __restrict__ emb,
                              const float* __restrict__ Wih_f, const float* __restrict__ bih_f,
                              const float* __restrict__ bhh_f,
                              const float* __restrict__ Wih_b, const float* __restrict__ bih_b,
                              const float* __restrict__ bhh_b, float* __restrict__ proj) {
    int dir = blockIdx.x, row = blockIdx.y, j = threadIdx.x;
    const float* W = dir ? Wih_b : Wih_f;
    const float* b1 = dir ? bih_b : bih_f;
    const float* b2 = dir ? bhh_b : bhh_f;
    float acc = b1[j] + b2[j];
    const float* e = emb + row * EMB;
    const float* w = W + j * EMB;
    for (int k = 0; k < EMB; ++k) acc += e[k] * w[k];
    proj[(dir * 26 + row) * 256 + j] = acc;
}

// LSTM: one block per (seq position, direction); 4 waves = 4 gates.
// float4 LDS matvec reads, tgt indices pre-staged, proj prefetched 1 step ahead.
__global__ __launch_bounds__(256) void lstm_kernel(const int* __restrict__ target,
                                                   const float* __restrict__ proj26,
                                                   const float* __restrict__ Whh_f,
                                                   const float* __restrict__ Whh_b,
                                                   float* __restrict__ hcat) {
    int n = blockIdx.x;
    int dir = blockIdx.y;
    int tid = threadIdx.x;
    const float* Whh = dir ? Whh_b : Whh_f;
    const float* proj = proj26 + dir * 26 * 256;
    const int gate = tid >> 6;  // 0=i 1=f 2=g 3=o
    float w[LH];
#pragma unroll
    for (int u4 = 0; u4 < LH / 4; ++u4) {
        float4 v = *reinterpret_cast<const float4*>(Whh + tid * LH + u4 * 4);
        w[u4 * 4 + 0] = v.x; w[u4 * 4 + 1] = v.y;
        w[u4 * 4 + 2] = v.z; w[u4 * 4 + 3] = v.w;
    }
    __shared__ float h_lds[LH];
    __shared__ float z_lds[256];
    __shared__ int tgt_lds[BB];   // per-step symbol, in iteration order
    float c_reg = 0.f;
    if (tid < LH) h_lds[tid] = 0.f;
    if (tid < BB) {
        int t = dir ? (BB - 1 - tid) : tid;
        tgt_lds[tid] = target[t * SEQ + n];
    }
    __syncthreads();
    float pnext = proj[tgt_lds[0] * 256 + tid];
    for (int s = 0; s < BB; ++s) {
        float a0 = 0.f, a1 = 0.f, a2 = 0.f, a3 = 0.f;
#pragma unroll
        for (int u = 0; u < LH; u += 4) {
            float4 hv = *reinterpret_cast<const float4*>(&h_lds[u]);
            a0 += w[u] * hv.x;
            a1 += w[u + 1] * hv.y;
            a2 += w[u + 2] * hv.z;
            a3 += w[u + 3] * hv.w;
        }
        float z = pnext + a0 + a1 + a2 + a3;
        if (s + 1 < BB) pnext = proj[tgt_lds[s + 1] * 256 + tid];  // prefetch
        z_lds[tid] = (gate == 2) ? fast_tanh(z) : fast_sigmoid(z);
        __syncthreads();
        if (tid < LH) {
            float ig = z_lds[tid];
            float fg = z_lds[LH + tid];
            float gg = z_lds[2 * LH + tid];
            float og = z_lds[3 * LH + tid];
            float c = fg * c_reg + ig * gg;
            float h = og * fast_tanh(c);
            c_reg = c;
            h_lds[tid] = h;
            int t = dir ? (BB - 1 - s) : s;
            hcat[((size_t)t * SEQ + n) * 128 + dir * LH + tid] = h;
        }
        __syncthreads();
    }
}

// hcat[b][i][h] f32 -> hcatT[b][h][i] bf16 (LDS tiled transpose)
__global__ __launch_bounds__(256) void transpose_hcat(const float* __restrict__ hcat,
                                                      unsigned short* __restrict__ hcatT) {
    int b = blockIdx.z;
    int i0 = blockIdx.y * 32;
    int h0 = blockIdx.x * 32;
    int th = threadIdx.x & 31;
    int ti = threadIdx.x >> 5;
    __shared__ float t[32][33];
#pragma unroll
    for (int r = 0; r < 4; ++r) {
        int i = i0 + ti + r * 8;
        if (i < SEQ) t[ti + r * 8][th] = hcat[((size_t)b * SEQ + i) * 128 + h0 + th];
    }
    __syncthreads();
#pragma unroll
    for (int r = 0; r < 4; ++r) {
        int h = h0 + ti + r * 8;
        int i = i0 + th;
        if (i < SEQ) {
            unsigned int u = __float_as_uint(t[th][ti + r * 8]);
            unsigned int lsb = (u >> 16) & 1u;
            u += 0x7fffu + lsb;
            hcatT[((size_t)b * 128 + h) * SEQ + i] = (unsigned short)(u >> 16);
        }
    }
}

// conv_w[o][i][k] f32 -> wT[o*8+k][i] bf16
__global__ void reshape_convw(const float* __restrict__ conv_w, __hip_bfloat16* __restrict__ wT) {
    int idx = blockIdx.x * blockDim.x + threadIdx.x;
    if (idx >= 256 * SEQ) return;
    int np = idx / SEQ, i = idx % SEQ;
    int o = np >> 3, k = np & 7;
    wT[idx] = __float2bfloat16(conv_w[((size_t)o * SEQ + i) * 8 + k]);
}

// out[b][o][p] = sum_k T[(b*128+p+k)][o*8+k] + conv_b[o]
__global__ void conv_finalize(const float* __restrict__ T, const float* __restrict__ conv_b,
                              float* __restrict__ convout) {
    int idx = blockIdx.x * blockDim.x + threadIdx.x;
    if (idx >= BB * 32 * 121) return;
    int p = idx % 121;
    int o = (idx / 121) % 32;
    int b = idx / (121 * 32);
    float acc = conv_b[o];
#pragma unroll
    for (int k = 0; k < 8; ++k)
        acc += T[(size_t)(b * 128 + p + k) * 256 + o * 8 + k];
    convout[(size_t)b * 3872 + o * 121 + p] = acc;
}

// ---------------- launcher ----------------
extern "C" void kernel_launch(void* const* d_in, const int* in_sizes, int n_in,
                              void* d_out, int out_size, void* d_ws, size_t ws_size,
                              hipStream_t stream) {
    const float* x      = (const float*)d_in[0];
    const int*   ei     = (const int*)d_in[1];
    const int*   batch  = (const int*)d_in[2];
    const int*   target = (const int*)d_in[3];
    const float* Wl     = (const float*)d_in[4];
    const float* Wr     = (const float*)d_in[5];
    const float* att    = (const float*)d_in[6];
    const float* gat_b  = (const float*)d_in[7];
    const float* gcn_w  = (const float*)d_in[8];
    const float* gcn_b  = (const float*)d_in[9];
    const float* emb    = (const float*)d_in[10];
    const float* Wih_f  = (const float*)d_in[11];
    const float* Whh_f  = (const float*)d_in[12];
    const float* bih_f  = (const float*)d_in[13];
    const float* bhh_f  = (const float*)d_in[14];
    const float* Wih_b  = (const float*)d_in[15];
    const float* Whh_b  = (const float*)d_in[16];
    const float* bih_b  = (const float*)d_in[17];
    const float* bhh_b  = (const float*)d_in[18];
    const float* conv_w = (const float*)d_in[19];
    const float* conv_b = (const float*)d_in[20];
    const float* fcp_w  = (const float*)d_in[21];
    const float* fcp_b  = (const float*)d_in[22];
    const float* fc1_w  = (const float*)d_in[23];
    const float* fc1_b  = (const float*)d_in[24];
    const float* fc2_w  = (const float*)d_in[25];
    const float* fc2_b  = (const float*)d_in[26];
    const float* out_w  = (const float*)d_in[27];
    const float* out_b  = (const float*)d_in[28];
    float* out = (float*)d_out;
    (void)n_in; (void)in_sizes; (void)out_size;

    // ---------- workspace layout ----------
    char* ws = (char*)d_ws;
    size_t o = 0;
    auto alloc = [&](size_t bytes) {
        char* p = ws + o;
        o = (o + bytes + 255) & ~(size_t)255;
        return p;
    };
    constexpr size_t HALF = (size_t)HH * NNP * CCP * 2; // 48.1 MB (one sliced matrix)
    // Union region: protein {hcat,proj26,convout,wT,hcatT,T} -> {xl|xr} -> {hw|g}
    char* region = (char*)alloc(2 * HALF);
    __hip_bfloat16* xl_sl = (__hip_bfloat16*)region;
    __hip_bfloat16* xr_sl = (__hip_bfloat16*)(region + HALF);
    __hip_bfloat16* hw_sl = (__hip_bfloat16*)region;          // after xl dead
    __hip_bfloat16* g_sl  = (__hip_bfloat16*)(region + HALF); // after xr dead
    // protein-phase sub-layout inside the union region
    char* rp = region;
    auto palloc = [&](size_t bytes) {
        char* p = rp;
        rp += (bytes + 255) & ~(size_t)255;
        return p;
    };
    float* hcat    = (float*)palloc((size_t)BB * SEQ * 128 * 4);   // 32.8 MB
    float* proj26  = (float*)palloc(2 * 26 * 256 * 4);             // 53 KB
    float* convout = (float*)palloc((size_t)BB * 3872 * 4);        // 1 MB
    __hip_bfloat16* wT = (__hip_bfloat16*)palloc((size_t)256 * SEQ * 2);        // 0.5 MB
    unsigned short* hcatT = (unsigned short*)palloc((size_t)BB * 128 * SEQ * 2); // 16.4 MB
    float* T = (float*)palloc((size_t)BB * 128 * 256 * 4);         // 8.4 MB
    // Persistent buffers
    __hip_bfloat16* h_bf  = (__hip_bfloat16*)alloc((size_t)NNP * DDP * 2); // dense padded (glds A)
    __hip_bfloat16* x_bf  = (__hip_bfloat16*)alloc((size_t)NNP * KXP * 2);
    __hip_bfloat16* wl_t  = (__hip_bfloat16*)alloc((size_t)NBP * KXP * 2);
    __hip_bfloat16* wr_t  = (__hip_bfloat16*)alloc((size_t)NBP * KXP * 2);
    __hip_bfloat16* gcw_t = (__hip_bfloat16*)alloc((size_t)NBP * DDP * 2);
    float* att_p  = (float*)alloc((size_t)HH * CCP * 4);
    float* fcp_wt = (float*)alloc((size_t)3872 * 128 * 4);
    float* fc1_wt = (float*)alloc((size_t)COMBD * 1024 * 4);
    float* fc2_wt = (float*)alloc((size_t)1024 * 512 * 4);
    float* out_wt = (float*)alloc((size_t)512 * 4);
    float* logit    = (float*)alloc((size_t)ET * HH * 4); // head-major; alpha in place
    int*   csr_src  = (int*)alloc((size_t)ET * 4);
    int*   csr_dst  = (int*)alloc((size_t)ET * 4);
    int*   deg      = (int*)alloc((size_t)NN * 4);
    int*   cursor   = (int*)alloc((size_t)NN * 4);
    int*   offs     = (int*)alloc((size_t)(NN + 1) * 4);
    float* dinv     = (float*)alloc((size_t)NN * 4);
    int*   gstart   = (int*)alloc(64 * 4);
    int*   gend     = (int*)alloc(64 * 4);
    float* pmax     = (float*)alloc((size_t)BB * DD * 4);
    float* psum     = (float*)alloc((size_t)BB * DD * 4);
    float* comb     = (float*)alloc((size_t)BB * COMBD * 4);
    float* h1       = (float*)alloc((size_t)BB * 1024 * 4);
    float* h2       = (float*)alloc((size_t)BB * 512 * 4);
    if (o > ws_size) return;  // diagnostic: insufficient workspace -> no launches

    // zero scratch that is accumulated into
    hipMemsetAsync(deg, 0, (size_t)NN * 4, stream);
    hipMemsetAsync(cursor, 0, (size_t)NN * 4, stream);
    hipMemsetAsync(gstart, 0, 64 * 4, stream);
    hipMemsetAsync(gend, 0, 64 * 4, stream);
    hipMemsetAsync(pmax, 0, (size_t)BB * DD * 4, stream);
    hipMemsetAsync(psum, 0, (size_t)BB * DD * 4, stream);

    // ---------- protein branch (uses the union region first) ----------
    {
        dim3 grid(2, 26);
        proj26_kernel<<<grid, 256, 0, stream>>>(emb, Wih_f, bih_f, bhh_f, Wih_b, bih_b, bhh_b, proj26);
    }
    {
        dim3 grid(SEQ, 2);
        lstm_kernel<<<grid, 256, 0, stream>>>(target, proj26, Whh_f, Whh_b, hcat);
    }
    // conv as MFMA GEMM (K=1000 not %32 -> legacy staging kernel)
    {
        dim3 grid(4, 32, BB);
        transpose_hcat<<<grid, 256, 0, stream>>>(hcat, hcatT);
    }
    reshape_convw<<<(256 * SEQ + 255) / 256, 256, 0, stream>>>(conv_w, wT);
    {
        dim3 grid(2, 64);
        gemm_bf16_mfma<<<grid, 256, 0, stream>>>((const __hip_bfloat16*)hcatT, wT, T,
                                                 BB * 128, 256, SEQ, 256);
    }
    conv_finalize<<<(BB * 32 * 121 + 255) / 256, 256, 0, stream>>>(T, conv_b, convout);
    transpose_f32<<<(3872 * 128 + 255) / 256, 256, 0, stream>>>(fcp_w, fcp_wt, 3872, 128);
    gemm_skinny<0><<<(BB * 128 + 3) / 4, 256, 0, stream>>>(convout, fcp_wt, fcp_b,
                                                           comb + 2 * DD, BB, 128, 3872, COMBD);

    // ---------- conversions / padding ----------
    pad_x<<<(NNP * KXP + 255) / 256, 256, 0, stream>>>(x, x_bf);
    pad_wT<<<(NBP * KXP + 255) / 256, 256, 0, stream>>>(Wl, wl_t);
    pad_wT<<<(NBP * KXP + 255) / 256, 256, 0, stream>>>(Wr, wr_t);
    pad_gcwT<<<(NBP * DDP + 255) / 256, 256, 0, stream>>>(gcn_w, gcw_t);
    pad_att<<<(HH * CCP + 255) / 256, 256, 0, stream>>>(att, att_p);
    transpose_f32<<<(COMBD * 1024 + 255) / 256, 256, 0, stream>>>(fc1_w, fc1_wt, COMBD, 1024);
    transpose_f32<<<(1024 * 512 + 255) / 256, 256, 0, stream>>>(fc2_w, fc2_wt, 1024, 512);
    transpose_f32<<<(512 + 255) / 256, 256, 0, stream>>>(out_w, out_wt, 512, 1);

    // ---------- graph branch ----------
    dim3 ggrid((DD + 127) / 128, NNP / 128);   // 7 x 235
    gemm_glds_sl<<<ggrid, 256, 0, stream>>>(x_bf, wl_t, xl_sl, NN, DD, KXP);
    gemm_glds_sl<<<ggrid, 256, 0, stream>>>(x_bf, wr_t, xr_sl, NN, DD, KXP);
    zero_pads<<<(NN * HH + 255) / 256, 256, 0, stream>>>((unsigned int*)xl_sl, (unsigned int*)xr_sl);
    // CSR
    deg_count<<<(ET + 255) / 256, 256, 0, stream>>>(ei, deg);
    scan_kernel<<<1, 1024, 0, stream>>>(deg, offs);
    csr_fill<<<(ET + 255) / 256, 256, 0, stream>>>(ei, offs, cursor, csr_src, csr_dst);
    dinv_kernel<<<(NN + 255) / 256, 256, 0, stream>>>(deg, dinv);
    // GATv2: head-pure blocks for L2 locality on the xl gather
    {
        dim3 grid((ET + 255) / 256, HH);
        gat_logits<<<grid, 256, 0, stream>>>((const unsigned short*)xl_sl,
                                             (const unsigned short*)xr_sl,
                                             att_p, csr_src, csr_dst, logit);
    }
    gat_softmax<<<(NN * HH + 255) / 256, 256, 0, stream>>>(offs, logit);
    gat_aggregate<<<NN, 256, 0, stream>>>(offs, csr_src, logit,
                                          (const unsigned int*)xl_sl, gat_b,
                                          (unsigned int*)h_bf);
    // GCN: hw = h @ gcn_w^T via glds GEMM -> head-sliced hw
    {
        dim3 g2((DD + 127) / 128, NNP / 128);
        gemm_glds_sl<<<g2, 256, 0, stream>>>(h_bf, gcw_t, hw_sl, NN, DD, DDP);
    }
    gcn_aggregate<<<NN, 256, 0, stream>>>(offs, csr_src, dinv,
                                          (const unsigned int*)hw_sl, gcn_b,
                                          (unsigned int*)g_sl);
    // pooling -> comb[:, 0:1560]
    graph_ranges<<<(NN + 255) / 256, 256, 0, stream>>>(batch, gstart, gend);
    pool_partial<<<(NN + PCHUNK - 1) / PCHUNK, 256, 0, stream>>>((const unsigned int*)g_sl,
                                                                 batch, pmax, psum);
    pool_finalize<<<(BB * DD + 255) / 256, 256, 0, stream>>>(pmax, psum, gstart, gend, comb);

    // ---------- combined head ----------
    gemm_skinny<1><<<(BB * 1024 + 3) / 4, 256, 0, stream>>>(comb, fc1_wt, fc1_b, h1,
                                                            BB, 1024, COMBD, 1024);
    gemm_skinny<1><<<(BB * 512 + 3) / 4, 256, 0, stream>>>(h1, fc2_wt, fc2_b, h2,
                                                           BB, 512, 1024, 512);
    gemm_skinny<0><<<(BB + 3) / 4, 256, 0, stream>>>(h2, out_wt, out_b, out,
                                                     BB, 1, 512, 1);
}